// Round 13
// baseline (260.886 us; speedup 1.0000x reference)
//
#include <hip/hip_runtime.h>
#include <hip/hip_fp16.h>
#include <math.h>

// Problem constants (match reference file)
#define N_NODES 100000
#define N_EDGES 1600000
#define HID 64
#define NB 391        // node buckets of 256 nodes (100000>>8 -> 0..390)
#define CAP 4608      // bucket edge capacity: mean 4092, sigma~64 -> +8 sigma
#define SCAP (CAP + 256)  // srcs region per bucket (edges + self-loops)
#define L2E 1.4426950408889634f

// gfx950 VOP3P packed-fp16 ops on raw bit patterns (ROCm header lacks *_2 intrinsics)
__device__ __forceinline__ unsigned int pk_add(unsigned int a, unsigned int b) {
    unsigned int r;
    asm("v_pk_add_f16 %0, %1, %2" : "=v"(r) : "v"(a), "v"(b));
    return r;
}
__device__ __forceinline__ unsigned int pk_min0(unsigned int a) {
    unsigned int r;
    asm("v_pk_min_f16 %0, %1, %2" : "=v"(r) : "v"(a), "v"(0u));
    return r;
}
__device__ __forceinline__ unsigned int pk_max0(unsigned int a) {
    unsigned int r;
    asm("v_pk_max_f16 %0, %1, %2" : "=v"(r) : "v"(a), "v"(0u));
    return r;
}
__device__ __forceinline__ unsigned int pk_fma(unsigned int a, unsigned int b, unsigned int c) {
    unsigned int r;
    asm("v_pk_fma_f16 %0, %1, %2, %3" : "=v"(r) : "v"(a), "v"(b), "v"(c));
    return r;
}
__device__ __forceinline__ float h2lo(unsigned int u) { return __half2float(*(const __half*)&u); }
__device__ __forceinline__ float h2hi(unsigned int u) { unsigned short s = (unsigned short)(u >> 16); return __half2float(*(const __half*)&s); }

__device__ __forceinline__ uint4 pack_h8(const float* v) {
    __half2 a = __floats2half2_rn(v[0], v[1]);
    __half2 b = __floats2half2_rn(v[2], v[3]);
    __half2 c = __floats2half2_rn(v[4], v[5]);
    __half2 d = __floats2half2_rn(v[6], v[7]);
    uint4 u;
    u.x = *(unsigned int*)&a; u.y = *(unsigned int*)&b;
    u.z = *(unsigned int*)&c; u.w = *(unsigned int*)&d;
    return u;
}

// ---------------------------------------------------------------------------
// Transpose the three 64x64 weight matrices (one block each).
// ---------------------------------------------------------------------------
__global__ void k_transpose3(const float* __restrict__ Wl, const float* __restrict__ Wr,
                             const float* __restrict__ W2, float* __restrict__ WlT,
                             float* __restrict__ WrT, float* __restrict__ W2T) {
    const float* A; float* AT;
    if (blockIdx.x == 0)      { A = Wl; AT = WlT; }
    else if (blockIdx.x == 1) { A = Wr; AT = WrT; }
    else                      { A = W2; AT = W2T; }
    for (int e = threadIdx.x; e < HID * HID; e += 256)
        AT[(e & 63) * HID + (e >> 6)] = A[e];
}

// ---------------------------------------------------------------------------
// One-pass bucketed edge scatter. Packed entry: src | (dst&255)<<24.
// ---------------------------------------------------------------------------
__global__ void k_bin_scatter(const int* __restrict__ src, const int* __restrict__ dst,
                              int* __restrict__ gcur, unsigned int* __restrict__ binned) {
    __shared__ int hist[NB];
    __shared__ int base[NB];
    for (int t = threadIdx.x; t < NB; t += blockDim.x) hist[t] = 0;
    __syncthreads();
    int stride = gridDim.x * blockDim.x;
    int gid = blockIdx.x * blockDim.x + threadIdx.x;
    for (int e = gid; e < N_EDGES; e += stride)
        atomicAdd(&hist[dst[e] >> 8], 1);
    __syncthreads();
    for (int t = threadIdx.x; t < NB; t += blockDim.x) {
        int h = hist[t];
        base[t] = h ? atomicAdd(&gcur[t], h) : 0;
        hist[t] = 0;
    }
    __syncthreads();
    for (int e = gid; e < N_EDGES; e += stride) {
        int d = dst[e];
        int bkt = d >> 8;
        int off = base[bkt] + atomicAdd(&hist[bkt], 1);
        binned[(size_t)bkt * CAP + off] = (unsigned int)src[e] | ((unsigned int)(d & 255) << 24);
    }
}

// ---------------------------------------------------------------------------
// Per-bucket: count -> scan -> node meta (rowbeg/rowend/dinv/xs) -> CSR
// scatter (from LDS stash). One block per bucket, 256 threads.
// ---------------------------------------------------------------------------
__global__ void __launch_bounds__(256) k_node_scan(
        const unsigned int* __restrict__ binned, const int* __restrict__ gcur,
        const float* __restrict__ x, int* __restrict__ rowbeg, int* __restrict__ rowend,
        float* __restrict__ dinv, float* __restrict__ xs, int* __restrict__ srcs) {
    __shared__ unsigned int stash[CAP];
    __shared__ int c[256];
    __shared__ int scan[256];
    int b = blockIdx.x, t = threadIdx.x;
    int n0 = b << 8;
    int ne = gcur[b];
    c[t] = 1;  // self-loop
    __syncthreads();
    for (int i = t; i < ne; i += 256) {
        unsigned int v = binned[(size_t)b * CAP + i];
        stash[i] = v;
        atomicAdd(&c[v >> 24], 1);
    }
    __syncthreads();
    int cnt = c[t];
    scan[t] = cnt;
    __syncthreads();
    for (int off = 1; off < 256; off <<= 1) {
        int add = (t >= off) ? scan[t - off] : 0;
        __syncthreads();
        scan[t] += add;
        __syncthreads();
    }
    int rb = b * SCAP + (scan[t] - cnt);  // exclusive, bucket-local srcs region
    int gn = n0 + t;
    if (gn < N_NODES) {
        rowbeg[gn] = rb;
        rowend[gn] = rb + cnt;
        float di = rsqrtf((float)cnt);
        dinv[gn] = di;
        float4 xv = ((const float4*)x)[gn];
        xv.x *= di; xv.y *= di; xv.z *= di; xv.w *= di;
        ((float4*)xs)[gn] = xv;
    }
    __syncthreads();
    c[t] = rb;  // cursors
    __syncthreads();
    for (int i = t; i < ne; i += 256) {
        unsigned int v = stash[i];
        int pos = atomicAdd(&c[v >> 24], 1);
        srcs[pos] = (int)(v & 0xFFFFFFu);
    }
    __syncthreads();
    if (gn < N_NODES) srcs[c[t]] = gn;  // self-loop in last slot
}

// ---------------------------------------------------------------------------
// Fused: GCN1 aggregation -> h1 = relu(aggx@W1+b1) -> hl (fp16), hr (fp16).
// Block = 256 thr = 32 nodes. Phase C uses transposed WlT/WrT (float4 loads).
// ---------------------------------------------------------------------------
__global__ void __launch_bounds__(256) k_aggx_hlhr(
        const int* __restrict__ rowbeg, const int* __restrict__ rowend,
        const int* __restrict__ srcs, const float* __restrict__ xs,
        const float* __restrict__ dinv, const float* __restrict__ W1,
        const float* __restrict__ b1, const float* __restrict__ WlT,
        const float* __restrict__ WrT, __half* __restrict__ hl,
        __half* __restrict__ hrh) {
    __shared__ float4 aggx_t[32];
    __shared__ float h1[32 * HID];
    int lane = threadIdx.x & 63;
    int w    = threadIdx.x >> 6;
    int g    = threadIdx.x >> 4;   // 16-lane group (0..15)
    int q    = threadIdx.x & 15;
    int n0   = blockIdx.x * 32;
#pragma unroll
    for (int k = 0; k < 2; ++k) {
        int n = g * 2 + k;
        int i = n0 + n;
        int rb = rowbeg[i], re = rowend[i];
        float4 acc = {0.f, 0.f, 0.f, 0.f};
        for (int p = rb + q; p < re; p += 16) {
            float4 v = ((const float4*)xs)[srcs[p]];
            acc.x += v.x; acc.y += v.y; acc.z += v.z; acc.w += v.w;
        }
#pragma unroll
        for (int mask = 1; mask <= 8; mask <<= 1) {
            acc.x += __shfl_xor(acc.x, mask);
            acc.y += __shfl_xor(acc.y, mask);
            acc.z += __shfl_xor(acc.z, mask);
            acc.w += __shfl_xor(acc.w, mask);
        }
        if (q == 0) {
            float di = dinv[i];
            acc.x *= di; acc.y *= di; acc.z *= di; acc.w *= di;
            aggx_t[n] = acc;
        }
    }
    __syncthreads();
    float w10 = W1[0 * HID + lane], w11 = W1[1 * HID + lane];
    float w12 = W1[2 * HID + lane], w13 = W1[3 * HID + lane];
    float bb  = b1[lane];
#pragma unroll
    for (int j = 0; j < 8; ++j) {
        int n = w * 8 + j;
        float4 a = aggx_t[n];
        h1[n * HID + lane] = fmaxf(a.x * w10 + a.y * w11 + a.z * w12 + a.w * w13 + bb, 0.f);
    }
    __syncthreads();
    float al[8], ar[8];
#pragma unroll
    for (int j = 0; j < 8; ++j) { al[j] = 0.f; ar[j] = 0.f; }
    const float4* wlt = (const float4*)(WlT + (size_t)lane * HID);
    const float4* wrt = (const float4*)(WrT + (size_t)lane * HID);
#pragma unroll 2
    for (int k0 = 0; k0 < 16; ++k0) {
        float4 wl4 = wlt[k0];
        float4 wr4 = wrt[k0];
#pragma unroll
        for (int j = 0; j < 8; ++j) {
            const float4 hv = *(const float4*)(&h1[(w * 8 + j) * HID + k0 * 4]);
            al[j] += hv.x * wl4.x + hv.y * wl4.y + hv.z * wl4.z + hv.w * wl4.w;
            ar[j] += hv.x * wr4.x + hv.y * wr4.y + hv.z * wr4.z + hv.w * wr4.w;
        }
    }
#pragma unroll
    for (int j = 0; j < 8; ++j) {
        int gn = n0 + w * 8 + j;
        hl[(size_t)gn * HID + lane]  = __float2half(al[j]);
        hrh[(size_t)gn * HID + lane] = __float2half(ar[j]);
    }
}

// ---------------------------------------------------------------------------
// GATv2 softmax WITHOUT max-subtraction (logits tiny & bounded; fp32 exp safe).
// 2 nodes/wave, 4 groups x 8 lanes, lane owns 8 fp16 channels (uint4).
// Packed fp16 add/leaky via v_pk_* asm; att pre-scaled by log2e -> exp2f.
// ---------------------------------------------------------------------------
__global__ void __launch_bounds__(256) k_gat(
        const int* __restrict__ rowbeg, const int* __restrict__ rowend,
        const int* __restrict__ srcs,
        const __half* __restrict__ hl, const __half* __restrict__ hrh,
        const float* __restrict__ att, const float* __restrict__ gat_b,
        const float* __restrict__ dinv, __half* __restrict__ s2) {
    int lane = threadIdx.x & 63;
    int w    = threadIdx.x >> 6;
    int h    = lane >> 5;          // node within wave
    int g    = (lane & 31) >> 3;   // group 0..3
    int q    = lane & 7;           // slot within group
    int c0   = q * 8;              // 8 channels per lane
    int i    = blockIdx.x * 8 + w * 2 + h;
    unsigned int hri[4];
    float a8[8];
    {
        uint4 uh = *(const uint4*)(hrh + (size_t)i * HID + c0);
        hri[0] = uh.x; hri[1] = uh.y; hri[2] = uh.z; hri[3] = uh.w;
        const float4 u0 = *(const float4*)(att + c0);
        const float4 u1 = *(const float4*)(att + c0 + 4);
        a8[0] = u0.x * L2E; a8[1] = u0.y * L2E; a8[2] = u0.z * L2E; a8[3] = u0.w * L2E;
        a8[4] = u1.x * L2E; a8[5] = u1.y * L2E; a8[6] = u1.z * L2E; a8[7] = u1.w * L2E;
    }
    const unsigned int c02 = 0x32663266u;  // half2(0.2, 0.2)
    float denom = 0.f;
    float acc[8];
#pragma unroll
    for (int j = 0; j < 8; ++j) acc[j] = 0.f;
    int b = rowbeg[i], en = rowend[i];
    int p = b + g;
    for (; p + 4 < en; p += 8) {
        int s0 = srcs[p];
        int s1 = srcs[p + 4];
        uint4 u0 = *(const uint4*)(hl + (size_t)s0 * HID + c0);
        uint4 u1 = *(const uint4*)(hl + (size_t)s1 * HID + c0);
        const unsigned int* p0 = (const unsigned int*)&u0;
        const unsigned int* p1 = (const unsigned int*)&u1;
        float t0 = 0.f, t1 = 0.f;
#pragma unroll
        for (int k = 0; k < 4; ++k) {
            unsigned int e0 = pk_add(p0[k], hri[k]);
            unsigned int l0 = pk_fma(pk_min0(e0), c02, pk_max0(e0));
            t0 = fmaf(h2lo(l0), a8[2 * k], t0);
            t0 = fmaf(h2hi(l0), a8[2 * k + 1], t0);
            unsigned int e1 = pk_add(p1[k], hri[k]);
            unsigned int l1 = pk_fma(pk_min0(e1), c02, pk_max0(e1));
            t1 = fmaf(h2lo(l1), a8[2 * k], t1);
            t1 = fmaf(h2hi(l1), a8[2 * k + 1], t1);
        }
        t0 += __shfl_xor(t0, 1); t1 += __shfl_xor(t1, 1);
        t0 += __shfl_xor(t0, 2); t1 += __shfl_xor(t1, 2);
        float ex0 = exp2f(t0);
        float ex1 = exp2f(t1);
        denom += ex0 + ex1;
#pragma unroll
        for (int k = 0; k < 4; ++k) {
            acc[2 * k]     = fmaf(h2lo(p0[k]), ex0, acc[2 * k]);
            acc[2 * k + 1] = fmaf(h2hi(p0[k]), ex0, acc[2 * k + 1]);
            acc[2 * k]     = fmaf(h2lo(p1[k]), ex1, acc[2 * k]);
            acc[2 * k + 1] = fmaf(h2hi(p1[k]), ex1, acc[2 * k + 1]);
        }
    }
    if (p < en) {
        int s = srcs[p];
        uint4 u0 = *(const uint4*)(hl + (size_t)s * HID + c0);
        const unsigned int* p0 = (const unsigned int*)&u0;
        float t0 = 0.f;
#pragma unroll
        for (int k = 0; k < 4; ++k) {
            unsigned int e0 = pk_add(p0[k], hri[k]);
            unsigned int l0 = pk_fma(pk_min0(e0), c02, pk_max0(e0));
            t0 = fmaf(h2lo(l0), a8[2 * k], t0);
            t0 = fmaf(h2hi(l0), a8[2 * k + 1], t0);
        }
        t0 += __shfl_xor(t0, 1);
        t0 += __shfl_xor(t0, 2);
        float ex0 = exp2f(t0);
        denom += ex0;
#pragma unroll
        for (int k = 0; k < 4; ++k) {
            acc[2 * k]     = fmaf(h2lo(p0[k]), ex0, acc[2 * k]);
            acc[2 * k + 1] = fmaf(h2hi(p0[k]), ex0, acc[2 * k + 1]);
        }
    }
    // merge the 4 groups: plain sums (no max state)
#pragma unroll
    for (int mask = 8; mask <= 16; mask <<= 1) {
        denom += __shfl_xor(denom, mask);
#pragma unroll
        for (int j = 0; j < 8; ++j) acc[j] += __shfl_xor(acc[j], mask);
    }
    float inv = 1.f / (denom + 1e-16f);
    float gb8[8];
    {
        const float4 u0 = *(const float4*)(gat_b + c0);
        const float4 u1 = *(const float4*)(gat_b + c0 + 4);
        gb8[0] = u0.x; gb8[1] = u0.y; gb8[2] = u0.z; gb8[3] = u0.w;
        gb8[4] = u1.x; gb8[5] = u1.y; gb8[6] = u1.z; gb8[7] = u1.w;
    }
    float di = dinv[i];
    float o[8];
#pragma unroll
    for (int j = 0; j < 8; ++j) o[j] = fmaxf(acc[j] * inv + gb8[j], 0.f) * di;
    if (g == 0) *(uint4*)(s2 + (size_t)i * HID + c0) = pack_h8(o);
}

// ---------------------------------------------------------------------------
// GCN2 aggregation (mix-FMA, dinv fused) + transform (W2T float4 weight loads)
// + final linear. 2 nodes/wave, barrier-free across waves (R11 structure).
// ---------------------------------------------------------------------------
__global__ void __launch_bounds__(256) k_agg2_out(
        const int* __restrict__ rowbeg, const int* __restrict__ rowend,
        const int* __restrict__ srcs,
        const __half* __restrict__ s2, const float* __restrict__ dinv,
        const float* __restrict__ W2T, const float* __restrict__ b2,
        const float* __restrict__ out_w, const float* __restrict__ out_b,
        float* __restrict__ out) {
    __shared__ float lds[8][HID];
    int lane = threadIdx.x & 63;
    int w    = threadIdx.x >> 6;
    int h    = lane >> 5;
    int g    = (lane & 31) >> 3;
    int q    = lane & 7;
    int c0   = q * 8;
    int i    = blockIdx.x * 8 + w * 2 + h;
    float di = dinv[i];
    int b = rowbeg[i], en = rowend[i];
    float acc[8];
#pragma unroll
    for (int j = 0; j < 8; ++j) acc[j] = 0.f;
    int p = b + g;
    for (; p + 4 < en; p += 8) {
        int s0 = srcs[p];
        int s1 = srcs[p + 4];
        uint4 u0 = *(const uint4*)(s2 + (size_t)s0 * HID + c0);
        uint4 u1 = *(const uint4*)(s2 + (size_t)s1 * HID + c0);
        const unsigned int* p0 = (const unsigned int*)&u0;
        const unsigned int* p1 = (const unsigned int*)&u1;
#pragma unroll
        for (int k = 0; k < 4; ++k) {
            acc[2 * k]     = fmaf(h2lo(p0[k]), di, acc[2 * k]);
            acc[2 * k + 1] = fmaf(h2hi(p0[k]), di, acc[2 * k + 1]);
            acc[2 * k]     = fmaf(h2lo(p1[k]), di, acc[2 * k]);
            acc[2 * k + 1] = fmaf(h2hi(p1[k]), di, acc[2 * k + 1]);
        }
    }
    if (p < en) {
        int s = srcs[p];
        uint4 u0 = *(const uint4*)(s2 + (size_t)s * HID + c0);
        const unsigned int* p0 = (const unsigned int*)&u0;
#pragma unroll
        for (int k = 0; k < 4; ++k) {
            acc[2 * k]     = fmaf(h2lo(p0[k]), di, acc[2 * k]);
            acc[2 * k + 1] = fmaf(h2hi(p0[k]), di, acc[2 * k + 1]);
        }
    }
#pragma unroll
    for (int mask = 8; mask <= 16; mask <<= 1) {
#pragma unroll
        for (int j = 0; j < 8; ++j) acc[j] += __shfl_xor(acc[j], mask);
    }
    if (g == 0) {
        int n = w * 2 + h;
        *(float4*)(&lds[n][c0])     = make_float4(acc[0], acc[1], acc[2], acc[3]);
        *(float4*)(&lds[n][c0 + 4]) = make_float4(acc[4], acc[5], acc[6], acc[7]);
    }
    __syncthreads();
    // epilogue: wave computes z for its 2 nodes; W2T column as float4 (16 loads)
    const float4* r0 = (const float4*)lds[w * 2];
    const float4* r1 = (const float4*)lds[w * 2 + 1];
    const float4* wt = (const float4*)(W2T + (size_t)lane * HID);
    float z0 = 0.f, z1 = 0.f;
#pragma unroll 4
    for (int k0 = 0; k0 < 16; ++k0) {
        float4 wv = wt[k0];
        float4 h0 = r0[k0];
        float4 h1 = r1[k0];
        z0 += h0.x * wv.x + h0.y * wv.y + h0.z * wv.z + h0.w * wv.w;
        z1 += h1.x * wv.x + h1.y * wv.y + h1.z * wv.z + h1.w * wv.w;
    }
    float bb = b2[lane];
    z0 = fmaxf(z0 + bb, 0.f);
    z1 = fmaxf(z1 + bb, 0.f);
    float ww = out_w[lane];
    float y0 = z0 * ww, y1 = z1 * ww;
#pragma unroll
    for (int mask = 32; mask >= 1; mask >>= 1) {
        y0 += __shfl_xor(y0, mask);
        y1 += __shfl_xor(y1, mask);
    }
    if (lane == 0) {
        int nb = blockIdx.x * 8 + w * 2;
        float ob0 = out_b[0];
        out[nb]     = y0 + ob0;
        out[nb + 1] = y1 + ob0;
    }
}

// ---------------------------------------------------------------------------

extern "C" void kernel_launch(void* const* d_in, const int* in_sizes, int n_in,
                              void* d_out, int out_size, void* d_ws, size_t ws_size,
                              hipStream_t stream) {
    const float* x   = (const float*)d_in[0];
    const int*   ei  = (const int*)d_in[1];
    const int*   src = ei;
    const int*   dst = ei + N_EDGES;
    const float* W1  = (const float*)d_in[2];
    const float* b1  = (const float*)d_in[3];
    const float* Wl  = (const float*)d_in[4];
    const float* Wr  = (const float*)d_in[5];
    const float* att = (const float*)d_in[6];
    const float* gb  = (const float*)d_in[7];
    const float* W2  = (const float*)d_in[8];
    const float* b2  = (const float*)d_in[9];
    const float* ow  = (const float*)d_in[10];
    const float* ob  = (const float*)d_in[11];
    float* out = (float*)d_out;

    // workspace layout (256B-aligned regions)
    char* ws = (char*)d_ws;
    size_t o = 0;
    auto alloc = [&](size_t bytes) { size_t r = o; o = (o + bytes + 255) & ~(size_t)255; return r; };
    int*          gcur   = (int*)         (ws + alloc((size_t)NB * 4));
    unsigned int* binned = (unsigned int*)(ws + alloc((size_t)NB * CAP * 4));
    int*          srcs   = (int*)         (ws + alloc((size_t)NB * SCAP * 4));
    int*          rowbeg = (int*)         (ws + alloc((size_t)N_NODES * 4));
    int*          rowend = (int*)         (ws + alloc((size_t)N_NODES * 4));
    float*        dinv   = (float*)       (ws + alloc((size_t)N_NODES * 4));
    float*        xs     = (float*)       (ws + alloc((size_t)N_NODES * 4 * 4));
    __half*       hl     = (__half*)      (ws + alloc((size_t)N_NODES * HID * 2));
    __half*       hrh    = (__half*)      (ws + alloc((size_t)N_NODES * HID * 2));
    __half*       s2     = (__half*)      (ws + alloc((size_t)N_NODES * HID * 2));
    float*        WlT    = (float*)       (ws + alloc((size_t)HID * HID * 4));
    float*        WrT    = (float*)       (ws + alloc((size_t)HID * HID * 4));
    float*        W2T    = (float*)       (ws + alloc((size_t)HID * HID * 4));
    (void)ws_size; (void)n_in; (void)in_sizes; (void)out_size;

    const int nbG   = N_NODES / 32;       // 3125
    const int nbW2  = N_NODES / 8;        // 12500 (2 nodes/wave kernels, exact)

    (void)hipMemsetAsync(gcur, 0, (size_t)NB * 4, stream);
    k_transpose3<<<3, 256, 0, stream>>>(Wl, Wr, W2, WlT, WrT, W2T);
    k_bin_scatter<<<256, 1024, 0, stream>>>(src, dst, gcur, binned);
    k_node_scan<<<NB, 256, 0, stream>>>(binned, gcur, x, rowbeg, rowend, dinv, xs, srcs);
    k_aggx_hlhr<<<nbG, 256, 0, stream>>>(rowbeg, rowend, srcs, xs, dinv, W1, b1, WlT, WrT, hl, hrh);
    k_gat<<<nbW2, 256, 0, stream>>>(rowbeg, rowend, srcs, hl, hrh, att, gb, dinv, s2);
    k_agg2_out<<<nbW2, 256, 0, stream>>>(rowbeg, rowend, srcs, s2, dinv, W2T, b2, ow, ob, out);
}

// Round 14
// 192.064 us; speedup vs baseline: 1.3583x; 1.3583x over previous
//
#include <hip/hip_runtime.h>
#include <hip/hip_fp16.h>
#include <math.h>

// Problem constants (match reference file)
#define N_NODES 100000
#define N_EDGES 1600000
#define HID 64
#define NB 391        // node buckets of 256 nodes (100000>>8 -> 0..390)
#define CAP 4608      // bucket edge capacity: mean 4092, sigma~64 -> +8 sigma
#define SCAP (CAP + 256)  // srcs region per bucket (edges + self-loops)
#define L2E 1.4426950408889634f

// gfx950 VOP3P packed-fp16 ops on raw bit patterns (ROCm header lacks *_2 intrinsics)
__device__ __forceinline__ unsigned int pk_add(unsigned int a, unsigned int b) {
    unsigned int r;
    asm("v_pk_add_f16 %0, %1, %2" : "=v"(r) : "v"(a), "v"(b));
    return r;
}
__device__ __forceinline__ unsigned int pk_min0(unsigned int a) {
    unsigned int r;
    asm("v_pk_min_f16 %0, %1, %2" : "=v"(r) : "v"(a), "v"(0u));
    return r;
}
__device__ __forceinline__ unsigned int pk_max0(unsigned int a) {
    unsigned int r;
    asm("v_pk_max_f16 %0, %1, %2" : "=v"(r) : "v"(a), "v"(0u));
    return r;
}
__device__ __forceinline__ unsigned int pk_fma(unsigned int a, unsigned int b, unsigned int c) {
    unsigned int r;
    asm("v_pk_fma_f16 %0, %1, %2, %3" : "=v"(r) : "v"(a), "v"(b), "v"(c));
    return r;
}
__device__ __forceinline__ float h2lo(unsigned int u) { return __half2float(*(const __half*)&u); }
__device__ __forceinline__ float h2hi(unsigned int u) { unsigned short s = (unsigned short)(u >> 16); return __half2float(*(const __half*)&s); }

__device__ __forceinline__ uint4 pack_h8(const float* v) {
    __half2 a = __floats2half2_rn(v[0], v[1]);
    __half2 b = __floats2half2_rn(v[2], v[3]);
    __half2 c = __floats2half2_rn(v[4], v[5]);
    __half2 d = __floats2half2_rn(v[6], v[7]);
    uint4 u;
    u.x = *(unsigned int*)&a; u.y = *(unsigned int*)&b;
    u.z = *(unsigned int*)&c; u.w = *(unsigned int*)&d;
    return u;
}

// ---------------------------------------------------------------------------
// One-pass bucketed edge scatter. Packed entry: src | (dst&255)<<24.
// ---------------------------------------------------------------------------
__global__ void k_bin_scatter(const int* __restrict__ src, const int* __restrict__ dst,
                              int* __restrict__ gcur, unsigned int* __restrict__ binned) {
    __shared__ int hist[NB];
    __shared__ int base[NB];
    for (int t = threadIdx.x; t < NB; t += blockDim.x) hist[t] = 0;
    __syncthreads();
    int stride = gridDim.x * blockDim.x;
    int gid = blockIdx.x * blockDim.x + threadIdx.x;
    for (int e = gid; e < N_EDGES; e += stride)
        atomicAdd(&hist[dst[e] >> 8], 1);
    __syncthreads();
    for (int t = threadIdx.x; t < NB; t += blockDim.x) {
        int h = hist[t];
        base[t] = h ? atomicAdd(&gcur[t], h) : 0;
        hist[t] = 0;
    }
    __syncthreads();
    for (int e = gid; e < N_EDGES; e += stride) {
        int d = dst[e];
        int bkt = d >> 8;
        int off = base[bkt] + atomicAdd(&hist[bkt], 1);
        binned[(size_t)bkt * CAP + off] = (unsigned int)src[e] | ((unsigned int)(d & 255) << 24);
    }
}

// ---------------------------------------------------------------------------
// Per-bucket: count -> scan -> node meta (rowbeg/rowend/dinv/xs) -> CSR
// scatter (from LDS stash). One block per bucket, 256 threads.
// ---------------------------------------------------------------------------
__global__ void __launch_bounds__(256) k_node_scan(
        const unsigned int* __restrict__ binned, const int* __restrict__ gcur,
        const float* __restrict__ x, int* __restrict__ rowbeg, int* __restrict__ rowend,
        float* __restrict__ dinv, float* __restrict__ xs, int* __restrict__ srcs) {
    __shared__ unsigned int stash[CAP];
    __shared__ int c[256];
    __shared__ int scan[256];
    int b = blockIdx.x, t = threadIdx.x;
    int n0 = b << 8;
    int ne = gcur[b];
    c[t] = 1;  // self-loop
    __syncthreads();
    for (int i = t; i < ne; i += 256) {
        unsigned int v = binned[(size_t)b * CAP + i];
        stash[i] = v;
        atomicAdd(&c[v >> 24], 1);
    }
    __syncthreads();
    int cnt = c[t];
    scan[t] = cnt;
    __syncthreads();
    for (int off = 1; off < 256; off <<= 1) {
        int add = (t >= off) ? scan[t - off] : 0;
        __syncthreads();
        scan[t] += add;
        __syncthreads();
    }
    int rb = b * SCAP + (scan[t] - cnt);  // exclusive, bucket-local srcs region
    int gn = n0 + t;
    if (gn < N_NODES) {
        rowbeg[gn] = rb;
        rowend[gn] = rb + cnt;
        float di = rsqrtf((float)cnt);
        dinv[gn] = di;
        float4 xv = ((const float4*)x)[gn];
        xv.x *= di; xv.y *= di; xv.z *= di; xv.w *= di;
        ((float4*)xs)[gn] = xv;
    }
    __syncthreads();
    c[t] = rb;  // cursors
    __syncthreads();
    for (int i = t; i < ne; i += 256) {
        unsigned int v = stash[i];
        int pos = atomicAdd(&c[v >> 24], 1);
        srcs[pos] = (int)(v & 0xFFFFFFu);
    }
    __syncthreads();
    if (gn < N_NODES) srcs[c[t]] = gn;  // self-loop in last slot
}

// ---------------------------------------------------------------------------
// Fused: GCN1 aggregation -> h1 = relu(aggx@W1+b1) -> hl (fp16), hr (fp16).
// Block = 256 thr = 32 nodes. Weight loads coalesced (W[k*HID+lane]).
// ---------------------------------------------------------------------------
__global__ void __launch_bounds__(256) k_aggx_hlhr(
        const int* __restrict__ rowbeg, const int* __restrict__ rowend,
        const int* __restrict__ srcs, const float* __restrict__ xs,
        const float* __restrict__ dinv, const float* __restrict__ W1,
        const float* __restrict__ b1, const float* __restrict__ Wl,
        const float* __restrict__ Wr, __half* __restrict__ hl,
        __half* __restrict__ hrh) {
    __shared__ float4 aggx_t[32];
    __shared__ float h1[32 * HID];
    int lane = threadIdx.x & 63;
    int w    = threadIdx.x >> 6;
    int g    = threadIdx.x >> 4;   // 16-lane group (0..15)
    int q    = threadIdx.x & 15;
    int n0   = blockIdx.x * 32;
#pragma unroll
    for (int k = 0; k < 2; ++k) {
        int n = g * 2 + k;
        int i = n0 + n;
        int rb = rowbeg[i], re = rowend[i];
        float4 acc = {0.f, 0.f, 0.f, 0.f};
        for (int p = rb + q; p < re; p += 16) {
            float4 v = ((const float4*)xs)[srcs[p]];
            acc.x += v.x; acc.y += v.y; acc.z += v.z; acc.w += v.w;
        }
#pragma unroll
        for (int mask = 1; mask <= 8; mask <<= 1) {
            acc.x += __shfl_xor(acc.x, mask);
            acc.y += __shfl_xor(acc.y, mask);
            acc.z += __shfl_xor(acc.z, mask);
            acc.w += __shfl_xor(acc.w, mask);
        }
        if (q == 0) {
            float di = dinv[i];
            acc.x *= di; acc.y *= di; acc.z *= di; acc.w *= di;
            aggx_t[n] = acc;
        }
    }
    __syncthreads();
    float w10 = W1[0 * HID + lane], w11 = W1[1 * HID + lane];
    float w12 = W1[2 * HID + lane], w13 = W1[3 * HID + lane];
    float bb  = b1[lane];
#pragma unroll
    for (int j = 0; j < 8; ++j) {
        int n = w * 8 + j;
        float4 a = aggx_t[n];
        h1[n * HID + lane] = fmaxf(a.x * w10 + a.y * w11 + a.z * w12 + a.w * w13 + bb, 0.f);
    }
    __syncthreads();
    float al[8], ar[8];
#pragma unroll
    for (int j = 0; j < 8; ++j) { al[j] = 0.f; ar[j] = 0.f; }
#pragma unroll 2
    for (int k0 = 0; k0 < 16; ++k0) {
        float wl0 = Wl[(k0 * 4 + 0) * HID + lane];
        float wl1 = Wl[(k0 * 4 + 1) * HID + lane];
        float wl2 = Wl[(k0 * 4 + 2) * HID + lane];
        float wl3 = Wl[(k0 * 4 + 3) * HID + lane];
        float wr0 = Wr[(k0 * 4 + 0) * HID + lane];
        float wr1 = Wr[(k0 * 4 + 1) * HID + lane];
        float wr2 = Wr[(k0 * 4 + 2) * HID + lane];
        float wr3 = Wr[(k0 * 4 + 3) * HID + lane];
#pragma unroll
        for (int j = 0; j < 8; ++j) {
            const float4 hv = *(const float4*)(&h1[(w * 8 + j) * HID + k0 * 4]);
            al[j] += hv.x * wl0 + hv.y * wl1 + hv.z * wl2 + hv.w * wl3;
            ar[j] += hv.x * wr0 + hv.y * wr1 + hv.z * wr2 + hv.w * wr3;
        }
    }
#pragma unroll
    for (int j = 0; j < 8; ++j) {
        int gn = n0 + w * 8 + j;
        hl[(size_t)gn * HID + lane]  = __float2half(al[j]);
        hrh[(size_t)gn * HID + lane] = __float2half(ar[j]);
    }
}

// ---------------------------------------------------------------------------
// GATv2 softmax WITHOUT max-subtraction (logits tiny & bounded; fp32 exp safe).
// 2 nodes/wave, 4 groups x 8 lanes, lane owns 8 fp16 channels (uint4).
// Packed fp16 add/leaky via v_pk_* asm; att pre-scaled by log2e -> exp2f.
// ---------------------------------------------------------------------------
__global__ void __launch_bounds__(256) k_gat(
        const int* __restrict__ rowbeg, const int* __restrict__ rowend,
        const int* __restrict__ srcs,
        const __half* __restrict__ hl, const __half* __restrict__ hrh,
        const float* __restrict__ att, const float* __restrict__ gat_b,
        const float* __restrict__ dinv, __half* __restrict__ s2) {
    int lane = threadIdx.x & 63;
    int w    = threadIdx.x >> 6;
    int h    = lane >> 5;          // node within wave
    int g    = (lane & 31) >> 3;   // group 0..3
    int q    = lane & 7;           // slot within group
    int c0   = q * 8;              // 8 channels per lane
    int i    = blockIdx.x * 8 + w * 2 + h;
    unsigned int hri[4];
    float a8[8];
    {
        uint4 uh = *(const uint4*)(hrh + (size_t)i * HID + c0);
        hri[0] = uh.x; hri[1] = uh.y; hri[2] = uh.z; hri[3] = uh.w;
        const float4 u0 = *(const float4*)(att + c0);
        const float4 u1 = *(const float4*)(att + c0 + 4);
        a8[0] = u0.x * L2E; a8[1] = u0.y * L2E; a8[2] = u0.z * L2E; a8[3] = u0.w * L2E;
        a8[4] = u1.x * L2E; a8[5] = u1.y * L2E; a8[6] = u1.z * L2E; a8[7] = u1.w * L2E;
    }
    const unsigned int c02 = 0x32663266u;  // half2(0.2, 0.2)
    float denom = 0.f;
    float acc[8];
#pragma unroll
    for (int j = 0; j < 8; ++j) acc[j] = 0.f;
    int b = rowbeg[i], en = rowend[i];
    int p = b + g;
    for (; p + 4 < en; p += 8) {
        int s0 = srcs[p];
        int s1 = srcs[p + 4];
        uint4 u0 = *(const uint4*)(hl + (size_t)s0 * HID + c0);
        uint4 u1 = *(const uint4*)(hl + (size_t)s1 * HID + c0);
        const unsigned int* p0 = (const unsigned int*)&u0;
        const unsigned int* p1 = (const unsigned int*)&u1;
        float t0 = 0.f, t1 = 0.f;
#pragma unroll
        for (int k = 0; k < 4; ++k) {
            unsigned int e0 = pk_add(p0[k], hri[k]);
            unsigned int l0 = pk_fma(pk_min0(e0), c02, pk_max0(e0));
            t0 = fmaf(h2lo(l0), a8[2 * k], t0);
            t0 = fmaf(h2hi(l0), a8[2 * k + 1], t0);
            unsigned int e1 = pk_add(p1[k], hri[k]);
            unsigned int l1 = pk_fma(pk_min0(e1), c02, pk_max0(e1));
            t1 = fmaf(h2lo(l1), a8[2 * k], t1);
            t1 = fmaf(h2hi(l1), a8[2 * k + 1], t1);
        }
        t0 += __shfl_xor(t0, 1); t1 += __shfl_xor(t1, 1);
        t0 += __shfl_xor(t0, 2); t1 += __shfl_xor(t1, 2);
        float ex0 = exp2f(t0);
        float ex1 = exp2f(t1);
        denom += ex0 + ex1;
#pragma unroll
        for (int k = 0; k < 4; ++k) {
            acc[2 * k]     = fmaf(h2lo(p0[k]), ex0, acc[2 * k]);
            acc[2 * k + 1] = fmaf(h2hi(p0[k]), ex0, acc[2 * k + 1]);
            acc[2 * k]     = fmaf(h2lo(p1[k]), ex1, acc[2 * k]);
            acc[2 * k + 1] = fmaf(h2hi(p1[k]), ex1, acc[2 * k + 1]);
        }
    }
    if (p < en) {
        int s = srcs[p];
        uint4 u0 = *(const uint4*)(hl + (size_t)s * HID + c0);
        const unsigned int* p0 = (const unsigned int*)&u0;
        float t0 = 0.f;
#pragma unroll
        for (int k = 0; k < 4; ++k) {
            unsigned int e0 = pk_add(p0[k], hri[k]);
            unsigned int l0 = pk_fma(pk_min0(e0), c02, pk_max0(e0));
            t0 = fmaf(h2lo(l0), a8[2 * k], t0);
            t0 = fmaf(h2hi(l0), a8[2 * k + 1], t0);
        }
        t0 += __shfl_xor(t0, 1);
        t0 += __shfl_xor(t0, 2);
        float ex0 = exp2f(t0);
        denom += ex0;
#pragma unroll
        for (int k = 0; k < 4; ++k) {
            acc[2 * k]     = fmaf(h2lo(p0[k]), ex0, acc[2 * k]);
            acc[2 * k + 1] = fmaf(h2hi(p0[k]), ex0, acc[2 * k + 1]);
        }
    }
    // merge the 4 groups: plain sums (no max state)
#pragma unroll
    for (int mask = 8; mask <= 16; mask <<= 1) {
        denom += __shfl_xor(denom, mask);
#pragma unroll
        for (int j = 0; j < 8; ++j) acc[j] += __shfl_xor(acc[j], mask);
    }
    float inv = 1.f / (denom + 1e-16f);
    float gb8[8];
    {
        const float4 u0 = *(const float4*)(gat_b + c0);
        const float4 u1 = *(const float4*)(gat_b + c0 + 4);
        gb8[0] = u0.x; gb8[1] = u0.y; gb8[2] = u0.z; gb8[3] = u0.w;
        gb8[4] = u1.x; gb8[5] = u1.y; gb8[6] = u1.z; gb8[7] = u1.w;
    }
    float di = dinv[i];
    float o[8];
#pragma unroll
    for (int j = 0; j < 8; ++j) o[j] = fmaxf(acc[j] * inv + gb8[j], 0.f) * di;
    if (g == 0) *(uint4*)(s2 + (size_t)i * HID + c0) = pack_h8(o);
}

// ---------------------------------------------------------------------------
// GCN2 aggregation (mix-FMA, dinv fused per-edge) + transform + final linear.
// 2 nodes/wave, barrier-free across waves; coalesced W2 weight loads.
// ---------------------------------------------------------------------------
__global__ void __launch_bounds__(256) k_agg2_out(
        const int* __restrict__ rowbeg, const int* __restrict__ rowend,
        const int* __restrict__ srcs,
        const __half* __restrict__ s2, const float* __restrict__ dinv,
        const float* __restrict__ W2, const float* __restrict__ b2,
        const float* __restrict__ out_w, const float* __restrict__ out_b,
        float* __restrict__ out) {
    __shared__ float lds[8][HID];
    int lane = threadIdx.x & 63;
    int w    = threadIdx.x >> 6;
    int h    = lane >> 5;
    int g    = (lane & 31) >> 3;
    int q    = lane & 7;
    int c0   = q * 8;
    int i    = blockIdx.x * 8 + w * 2 + h;
    float di = dinv[i];
    int b = rowbeg[i], en = rowend[i];
    float acc[8];
#pragma unroll
    for (int j = 0; j < 8; ++j) acc[j] = 0.f;
    int p = b + g;
    for (; p + 4 < en; p += 8) {
        int s0 = srcs[p];
        int s1 = srcs[p + 4];
        uint4 u0 = *(const uint4*)(s2 + (size_t)s0 * HID + c0);
        uint4 u1 = *(const uint4*)(s2 + (size_t)s1 * HID + c0);
        const unsigned int* p0 = (const unsigned int*)&u0;
        const unsigned int* p1 = (const unsigned int*)&u1;
#pragma unroll
        for (int k = 0; k < 4; ++k) {
            acc[2 * k]     = fmaf(h2lo(p0[k]), di, acc[2 * k]);
            acc[2 * k + 1] = fmaf(h2hi(p0[k]), di, acc[2 * k + 1]);
            acc[2 * k]     = fmaf(h2lo(p1[k]), di, acc[2 * k]);
            acc[2 * k + 1] = fmaf(h2hi(p1[k]), di, acc[2 * k + 1]);
        }
    }
    if (p < en) {
        int s = srcs[p];
        uint4 u0 = *(const uint4*)(s2 + (size_t)s * HID + c0);
        const unsigned int* p0 = (const unsigned int*)&u0;
#pragma unroll
        for (int k = 0; k < 4; ++k) {
            acc[2 * k]     = fmaf(h2lo(p0[k]), di, acc[2 * k]);
            acc[2 * k + 1] = fmaf(h2hi(p0[k]), di, acc[2 * k + 1]);
        }
    }
#pragma unroll
    for (int mask = 8; mask <= 16; mask <<= 1) {
#pragma unroll
        for (int j = 0; j < 8; ++j) acc[j] += __shfl_xor(acc[j], mask);
    }
    if (g == 0) {
        int n = w * 2 + h;
        *(float4*)(&lds[n][c0])     = make_float4(acc[0], acc[1], acc[2], acc[3]);
        *(float4*)(&lds[n][c0 + 4]) = make_float4(acc[4], acc[5], acc[6], acc[7]);
    }
    __syncthreads();
    // epilogue: wave computes z for its 2 nodes; coalesced W2 loads shared
    const float4* r0 = (const float4*)lds[w * 2];
    const float4* r1 = (const float4*)lds[w * 2 + 1];
    float z0 = 0.f, z1 = 0.f;
#pragma unroll 4
    for (int k0 = 0; k0 < 16; ++k0) {
        float w20 = W2[(k0 * 4 + 0) * HID + lane];
        float w21 = W2[(k0 * 4 + 1) * HID + lane];
        float w22 = W2[(k0 * 4 + 2) * HID + lane];
        float w23 = W2[(k0 * 4 + 3) * HID + lane];
        float4 h0 = r0[k0];
        float4 h1 = r1[k0];
        z0 += h0.x * w20 + h0.y * w21 + h0.z * w22 + h0.w * w23;
        z1 += h1.x * w20 + h1.y * w21 + h1.z * w22 + h1.w * w23;
    }
    float bb = b2[lane];
    z0 = fmaxf(z0 + bb, 0.f);
    z1 = fmaxf(z1 + bb, 0.f);
    float ww = out_w[lane];
    float y0 = z0 * ww, y1 = z1 * ww;
#pragma unroll
    for (int mask = 32; mask >= 1; mask >>= 1) {
        y0 += __shfl_xor(y0, mask);
        y1 += __shfl_xor(y1, mask);
    }
    if (lane == 0) {
        int nb = blockIdx.x * 8 + w * 2;
        float ob0 = out_b[0];
        out[nb]     = y0 + ob0;
        out[nb + 1] = y1 + ob0;
    }
}

// ---------------------------------------------------------------------------

extern "C" void kernel_launch(void* const* d_in, const int* in_sizes, int n_in,
                              void* d_out, int out_size, void* d_ws, size_t ws_size,
                              hipStream_t stream) {
    const float* x   = (const float*)d_in[0];
    const int*   ei  = (const int*)d_in[1];
    const int*   src = ei;
    const int*   dst = ei + N_EDGES;
    const float* W1  = (const float*)d_in[2];
    const float* b1  = (const float*)d_in[3];
    const float* Wl  = (const float*)d_in[4];
    const float* Wr  = (const float*)d_in[5];
    const float* att = (const float*)d_in[6];
    const float* gb  = (const float*)d_in[7];
    const float* W2  = (const float*)d_in[8];
    const float* b2  = (const float*)d_in[9];
    const float* ow  = (const float*)d_in[10];
    const float* ob  = (const float*)d_in[11];
    float* out = (float*)d_out;

    // workspace layout (256B-aligned regions)
    char* ws = (char*)d_ws;
    size_t o = 0;
    auto alloc = [&](size_t bytes) { size_t r = o; o = (o + bytes + 255) & ~(size_t)255; return r; };
    int*          gcur   = (int*)         (ws + alloc((size_t)NB * 4));
    unsigned int* binned = (unsigned int*)(ws + alloc((size_t)NB * CAP * 4));
    int*          srcs   = (int*)         (ws + alloc((size_t)NB * SCAP * 4));
    int*          rowbeg = (int*)         (ws + alloc((size_t)N_NODES * 4));
    int*          rowend = (int*)         (ws + alloc((size_t)N_NODES * 4));
    float*        dinv   = (float*)       (ws + alloc((size_t)N_NODES * 4));
    float*        xs     = (float*)       (ws + alloc((size_t)N_NODES * 4 * 4));
    __half*       hl     = (__half*)      (ws + alloc((size_t)N_NODES * HID * 2));
    __half*       hrh    = (__half*)      (ws + alloc((size_t)N_NODES * HID * 2));
    __half*       s2     = (__half*)      (ws + alloc((size_t)N_NODES * HID * 2));
    (void)ws_size; (void)n_in; (void)in_sizes; (void)out_size;

    const int nbG   = N_NODES / 32;       // 3125
    const int nbW2  = N_NODES / 8;        // 12500 (2 nodes/wave kernels, exact)

    (void)hipMemsetAsync(gcur, 0, (size_t)NB * 4, stream);
    k_bin_scatter<<<256, 1024, 0, stream>>>(src, dst, gcur, binned);
    k_node_scan<<<NB, 256, 0, stream>>>(binned, gcur, x, rowbeg, rowend, dinv, xs, srcs);
    k_aggx_hlhr<<<nbG, 256, 0, stream>>>(rowbeg, rowend, srcs, xs, dinv, W1, b1, Wl, Wr, hl, hrh);
    k_gat<<<nbW2, 256, 0, stream>>>(rowbeg, rowend, srcs, hl, hrh, att, gb, dinv, s2);
    k_agg2_out<<<nbW2, 256, 0, stream>>>(rowbeg, rowend, srcs, s2, dinv, W2, b2, ow, ob, out);
}